// Round 1
// baseline (547.352 us; speedup 1.0000x reference)
//
#include <hip/hip_runtime.h>

// Locally-connected conv, MI355X.
// Block = (h, 4-wide w strip, 32-wide o half); all 32 batches.
// Per position it's a 32(b) x 32(o) x 288(k) GEMM -> mfma_f32_32x32x16_bf16.
// Weight (288 MiB) streamed from HBM exactly once, staged bf16 in LDS.
// K processed in 4 chunks of 72 (8 channels * 9 taps), padded to 80 with zeros.

#define KP 88           // padded LDS row pitch in bf16 elems (16B-aligned rows)
#define NPOS 4          // w positions per block

typedef __attribute__((ext_vector_type(8))) short short8;
typedef __attribute__((ext_vector_type(16))) float f32x16;

__device__ __forceinline__ unsigned f2bf(float f) {
    unsigned u = __builtin_bit_cast(unsigned, f);
    return (u + 0x7FFFu + ((u >> 16) & 1u)) >> 16;   // RNE, inputs are finite
}

__global__ __launch_bounds__(256) void lcconv_kernel(
    const float* __restrict__ xg,    // [32][32][64][64]
    const float* __restrict__ wg,    // [64][64][64][32][3][3]
    const float* __restrict__ bg,    // [64][64][64]
    float* __restrict__ outg)        // [32][64][64][64]
{
    __shared__ unsigned short Wl[NPOS * 32 * KP];   // 22528 B, [p][o][k]
    __shared__ unsigned short Pl[NPOS * 32 * KP];   // 22528 B, [p][b][k]

    const int tid = threadIdx.x;
    const int bid = blockIdx.x;
    const int oh = bid & 1;            // o half
    const int ws = (bid >> 1) & 15;    // w strip
    const int h  = bid >> 5;           // 0..63
    const int w0 = ws * 4;
    const int og = oh * 32;

    // Zero the MFMA-visible pad region k in [72,80) once (data writes cover k<72).
    {
        unsigned short* base = (tid & 128) ? Pl : Wl;
        int row = tid & 127;
        *(short8*)(base + row * KP + 72) = (short8)0;
    }

    f32x16 acc;
#pragma unroll
    for (int i = 0; i < 16; i++) acc[i] = 0.f;

    const int lane = tid & 63;
    const int wv   = tid >> 6;     // wave id == position p
    const int mrow = lane & 31;    // A: m=b   B: n=o
    const int g    = lane >> 5;    // k-half select

    for (int cc = 0; cc < 4; cc++) {
        const int c0 = cc * 8;
        __syncthreads();   // prev chunk's MFMA reads done before restaging

        // ---- stage W chunk: 4 pos * 32 o * 72 k = 2304 float4, coalesced runs of 18
#pragma unroll
        for (int it = 0; it < 9; it++) {
            int f4 = it * 256 + tid;
            int run = f4 / 18;               // (p,o) pair
            int within = f4 - run * 18;      // float4 index inside 72-float run
            int p = run >> 5, o = run & 31;
            const float4 w4 = *(const float4*)(
                wg + ((h * 64 + (w0 + p)) * 64 + og + o) * 288 + c0 * 9 + within * 4);
            unsigned long long pk = (unsigned long long)f2bf(w4.x)
                | ((unsigned long long)f2bf(w4.y) << 16)
                | ((unsigned long long)f2bf(w4.z) << 32)
                | ((unsigned long long)f2bf(w4.w) << 48);
            *(unsigned long long*)(Wl + (p * 32 + o) * KP + within * 4) = pk;
        }

        // ---- stage P chunk (im2col): 4 pos * 32 b * 72 k = 4608 bf16-pairs
#pragma unroll
        for (int it = 0; it < 18; it++) {
            int pr = it * 256 + tid;
            int e = pr * 2;                  // even k
            int p = e / 2304;
            int rem = e - p * 2304;
            int b = rem / 72;
            int k = rem - b * 72;
            unsigned pk = 0;
#pragma unroll
            for (int half = 0; half < 2; half++) {
                int kk = k + half;
                int c  = kk / 9;
                int r9 = kk - c * 9;
                int i3 = r9 / 3;
                int j  = r9 - i3 * 3;
                int y  = h + i3 - 1;
                int xx = w0 + p + j - 1;
                float v = (y >= 0 && y < 64 && xx >= 0 && xx < 64)
                        ? xg[((b * 32 + c0 + c) * 64 + y) * 64 + xx] : 0.f;
                pk |= f2bf(v) << (16 * half);
            }
            *(unsigned*)(Pl + (p * 32 + b) * KP + k) = pk;
        }
        __syncthreads();

        // ---- MFMA: wave wv handles position wv; K chunk = 80 (incl. zero pad) = 5 steps
#pragma unroll
        for (int ks = 0; ks < 5; ks++) {
            short8 a  = *(const short8*)(Pl + (wv * 32 + mrow) * KP + ks * 16 + g * 8);
            short8 b8 = *(const short8*)(Wl + (wv * 32 + mrow) * KP + ks * 16 + g * 8);
            acc = __builtin_amdgcn_mfma_f32_32x32x16_bf16(a, b8, acc, 0, 0, 0);
        }
    }
    __syncthreads();

    // ---- epilogue: C frags -> LDS transpose (reuse Wl) -> coalesced-ish stores
    float* outl = (float*)Wl;   // [p][b][o] fp32, 16384 B <= 22528 B
#pragma unroll
    for (int r = 0; r < 16; r++) {
        int row = (r & 3) + 8 * (r >> 2) + 4 * g;   // b  (m74/m101-verified C layout)
        outl[(wv * 32 + row) * 32 + mrow] = acc[r]; // mrow = o_local
    }
    __syncthreads();

#pragma unroll
    for (int it = 0; it < 4; it++) {
        int id = it * 256 + tid;
        int b = id >> 5;
        int o = id & 31;
        float4 v;
        v.x = outl[0 * 1024 + b * 32 + o];
        v.y = outl[1 * 1024 + b * 32 + o];
        v.z = outl[2 * 1024 + b * 32 + o];
        v.w = outl[3 * 1024 + b * 32 + o];
        const float4 bb = *(const float4*)(bg + ((og + o) * 64 + h) * 64 + w0);
        v.x += bb.x; v.y += bb.y; v.z += bb.z; v.w += bb.w;
        *(float4*)(outg + ((b * 64 + og + o) * 64 + h) * 64 + w0) = v;
    }
}

extern "C" void kernel_launch(void* const* d_in, const int* in_sizes, int n_in,
                              void* d_out, int out_size, void* d_ws, size_t ws_size,
                              hipStream_t stream) {
    const float* x = (const float*)d_in[0];
    const float* w = (const float*)d_in[1];
    const float* b = (const float*)d_in[2];
    float* out = (float*)d_out;
    // grid: 64 h * 16 w-strips * 2 o-halves = 2048 blocks
    lcconv_kernel<<<dim3(2048), dim3(256), 0, stream>>>(x, w, b, out);
}

// Round 2
// 510.760 us; speedup vs baseline: 1.0716x; 1.0716x over previous
//
#include <hip/hip_runtime.h>

// Locally-connected conv, MI355X. Round 2.
// Block = (h, 4-wide w strip, 32-wide o half); all 32 batches.
// Per position: 32(b) x 32(o) x 288(k) GEMM -> mfma_f32_32x32x16_bf16.
// K in 4 chunks of 72 (8 ch * 9 taps), padded to 80 with zeros.
// R2 changes vs R1:
//  - im2col: coalesced float2 row loads + register bf16 convert + direct
//    LDS fan-out (col xc feeds taps with p+j=xc-1) — replaces 36 scalar
//    global gathers/thread/chunk that were the latency bottleneck.
//  - register prefetch of next chunk's W (9xfloat4) and x (12xfloat2)
//    issued right after the compute barrier, overlapping MFMA + staging.

#define KP 88           // LDS row pitch in bf16 elems (16B-aligned, 4-way max bank alias)

typedef __attribute__((ext_vector_type(8))) short short8;
typedef __attribute__((ext_vector_type(16))) float f32x16;

__device__ __forceinline__ unsigned f2bf(float f) {
    unsigned u = __builtin_bit_cast(unsigned, f);
    return (u + 0x7FFFu + ((u >> 16) & 1u)) >> 16;   // RNE, finite inputs
}

__global__ __launch_bounds__(256, 3) void lcconv_kernel(
    const float* __restrict__ xg,    // [32][32][64][64]
    const float* __restrict__ wg,    // [64][64][64][32][3][3]
    const float* __restrict__ bg,    // [64][64][64]
    float* __restrict__ outg)        // [32][64][64][64]
{
    __shared__ unsigned short Wl[4 * 32 * KP];   // [p][o][k]  22528 B
    __shared__ unsigned short Pl[4 * 32 * KP];   // [p][b][k]  22528 B

    const int tid = threadIdx.x;
    const int bid = blockIdx.x;
    const int oh = bid & 1;
    const int ws = (bid >> 1) & 15;
    const int h  = bid >> 5;
    const int w0 = ws * 4;
    const int og = oh * 32;

    // Zero MFMA-visible pad k in [72,80) once (data writes cover k<72 every chunk).
    {
        unsigned short* base = (tid & 128) ? Pl : Wl;
        int row = tid & 127;
        *(short8*)(base + row * KP + 72) = (short8)0;
    }

    f32x16 acc;
#pragma unroll
    for (int i = 0; i < 16; i++) acc[i] = 0.f;

    const int lane = tid & 63;
    const int wv   = tid >> 6;     // wave id == position p
    const int mrow = lane & 31;
    const int g    = lane >> 5;

    float4 wreg[9];
    float2 xreg[12];

    // ---- prefetch chunk 0
#pragma unroll
    for (int it = 0; it < 9; it++) {
        int f4 = it * 256 + tid;
        int run = f4 / 18, within = f4 - run * 18;
        int p = run >> 5, o = run & 31;
        wreg[it] = *(const float4*)(
            wg + ((h * 64 + (w0 + p)) * 64 + og + o) * 288 + within * 4);
    }
#pragma unroll
    for (int it = 0; it < 12; it++) {
        int task = it * 256 + tid;
        int f2i = task & 3, row = task >> 2;
        int b = row / 24, rem = row - b * 24;
        int c = rem / 3, y3 = rem - c * 3;
        int y = h + y3 - 1;
        int gx0 = w0 - 2 + 2 * f2i;
        if ((unsigned)y < 64u && (unsigned)gx0 < 64u)
            xreg[it] = *(const float2*)(xg + ((b * 32 + c) * 64 + y) * 64 + gx0);
        else
            xreg[it] = float2{0.f, 0.f};
    }

    for (int cc = 0; cc < 4; cc++) {
        __syncthreads();   // prev chunk's MFMA reads done

        // ---- W: registers -> LDS bf16
#pragma unroll
        for (int it = 0; it < 9; it++) {
            int f4 = it * 256 + tid;
            int run = f4 / 18, within = f4 - run * 18;
            float4 w4 = wreg[it];
            unsigned long long pk = (unsigned long long)f2bf(w4.x)
                | ((unsigned long long)f2bf(w4.y) << 16)
                | ((unsigned long long)f2bf(w4.z) << 32)
                | ((unsigned long long)f2bf(w4.w) << 48);
            *(unsigned long long*)(Wl + run * KP + within * 4) = pk;
        }

        // ---- x: registers -> bf16 -> fan-out im2col into Pl
        // col xc (0..7, global w = w0+xc-2) feeds taps (p,j) with p+j = xc-1.
#pragma unroll
        for (int it = 0; it < 12; it++) {
            int task = it * 256 + tid;
            int f2i = task & 3, row = task >> 2;
            int b = row / 24, rem = row - b * 24;
            int c = rem / 3, y3 = rem - c * 3;
            int kb = c * 9 + y3 * 3;
            int pb = b * KP + kb;
            unsigned bx0 = f2bf(xreg[it].x);
            unsigned bx1 = f2bf(xreg[it].y);
#pragma unroll
            for (int q = 0; q < 2; q++) {
                int xc = f2i * 2 + q;
                unsigned short bv = (unsigned short)(q ? bx1 : bx0);
#pragma unroll
                for (int j = 0; j < 3; j++) {
                    int p = xc - 1 - j;
                    if ((unsigned)p < 4u)
                        Pl[p * (32 * KP) + pb + j] = bv;
                }
            }
        }
        __syncthreads();

        // ---- prefetch next chunk while MFMAs run
        if (cc < 3) {
            const int c0n = (cc + 1) * 8;
#pragma unroll
            for (int it = 0; it < 9; it++) {
                int f4 = it * 256 + tid;
                int run = f4 / 18, within = f4 - run * 18;
                int p = run >> 5, o = run & 31;
                wreg[it] = *(const float4*)(
                    wg + ((h * 64 + (w0 + p)) * 64 + og + o) * 288 + c0n * 9 + within * 4);
            }
#pragma unroll
            for (int it = 0; it < 12; it++) {
                int task = it * 256 + tid;
                int f2i = task & 3, row = task >> 2;
                int b = row / 24, rem = row - b * 24;
                int c = rem / 3, y3 = rem - c * 3;
                int y = h + y3 - 1;
                int gx0 = w0 - 2 + 2 * f2i;
                if ((unsigned)y < 64u && (unsigned)gx0 < 64u)
                    xreg[it] = *(const float2*)(xg + ((b * 32 + c0n + c) * 64 + y) * 64 + gx0);
                else
                    xreg[it] = float2{0.f, 0.f};
            }
        }

        // ---- MFMA: wave wv = position; K chunk = 80 (incl. zero pad) = 5 steps
#pragma unroll
        for (int ks = 0; ks < 5; ks++) {
            short8 a  = *(const short8*)(Pl + (wv * 32 + mrow) * KP + ks * 16 + g * 8);
            short8 b8 = *(const short8*)(Wl + (wv * 32 + mrow) * KP + ks * 16 + g * 8);
            acc = __builtin_amdgcn_mfma_f32_32x32x16_bf16(a, b8, acc, 0, 0, 0);
        }
    }
    __syncthreads();

    // ---- epilogue: C frags -> LDS transpose (reuse Wl) -> float4 stores along w
    float* outl = (float*)Wl;   // [p][b][o] fp32, 16384 B
#pragma unroll
    for (int r = 0; r < 16; r++) {
        int row = (r & 3) + 8 * (r >> 2) + 4 * g;   // b (m74/m101 C layout, R1-verified)
        outl[(wv * 32 + row) * 32 + mrow] = acc[r];
    }
    __syncthreads();

#pragma unroll
    for (int it = 0; it < 4; it++) {
        int id = it * 256 + tid;
        int b = id >> 5;
        int o = id & 31;
        float4 v;
        v.x = outl[0 * 1024 + b * 32 + o];
        v.y = outl[1 * 1024 + b * 32 + o];
        v.z = outl[2 * 1024 + b * 32 + o];
        v.w = outl[3 * 1024 + b * 32 + o];
        const float4 bb = *(const float4*)(bg + ((og + o) * 64 + h) * 64 + w0);
        v.x += bb.x; v.y += bb.y; v.z += bb.z; v.w += bb.w;
        *(float4*)(outg + ((b * 64 + og + o) * 64 + h) * 64 + w0) = v;
    }
}

extern "C" void kernel_launch(void* const* d_in, const int* in_sizes, int n_in,
                              void* d_out, int out_size, void* d_ws, size_t ws_size,
                              hipStream_t stream) {
    const float* x = (const float*)d_in[0];
    const float* w = (const float*)d_in[1];
    const float* b = (const float*)d_in[2];
    float* out = (float*)d_out;
    lcconv_kernel<<<dim3(2048), dim3(256), 0, stream>>>(x, w, b, out);
}